// Round 7
// baseline (232.822 us; speedup 1.0000x reference)
//
#include <hip/hip_runtime.h>
#include <hip/hip_bf16.h>
#include <math.h>

#define NTOK 8192
#define DIM 256
#define KCB 4096
#define NCB (KCB / 128)    // 32 col-blocks in keysw layout
#define NKEY 4             // top-4 kept per (row, col-block)
#define NKROW (NCB * NKEY) // 128 u32 keys per row
#define DELTA 0.08f        // candidate window, raw-dot units (~20 sigma of bf16 noise + quant)
#define GTIE 2e-6          // fp64 cosine gap below which we run the bit-exact np chain
#define MAXC 16
#define NSCOB ((NTOK / 128) * NCB)    // 2048 score blocks (128x128)
#define NPAIRB (NCB * (NCB + 1) / 2)  // 528 pairwise upper-triangle blocks (128x128)

typedef unsigned long long ull;
typedef unsigned short ushort;
typedef __attribute__((ext_vector_type(8))) short shortx8;   // 8 bf16 (4 VGPRs)
typedef __attribute__((ext_vector_type(4))) float floatx4;

// ---- float <-> order-preserving u32 ----
__device__ __forceinline__ unsigned f2ord(float f) {
    unsigned u = __float_as_uint(f);
    return (u & 0x80000000u) ? ~u : (u | 0x80000000u);
}
__device__ __forceinline__ float ord2f(unsigned u) {
    unsigned b = (u & 0x80000000u) ? (u & 0x7FFFFFFFu) : ~u;
    return __uint_as_float(b);
}
__device__ __forceinline__ ushort f2bf(float f) {   // RNE fp32->bf16
    unsigned u = __float_as_uint(f);
    unsigned r = u + 0x7FFFu + ((u >> 16) & 1u);
    return (ushort)(r >> 16);
}

// ---- fused prep: 4 rows per block, one wave per row ----
// blocks [0, NTOK/4): latent rows; [NTOK/4, NTOK/4 + KCB/4): codebook rows
__global__ __launch_bounds__(256) void prep(const float* __restrict__ lat,
                                            const float* __restrict__ cb,
                                            float* __restrict__ nrml,
                                            float* __restrict__ nrmc,
                                            ushort* __restrict__ latbf,
                                            ushort* __restrict__ cnbf,
                                            ushort* __restrict__ cbbf,
                                            float* __restrict__ sq,
                                            unsigned* __restrict__ counts) {
    int bid = blockIdx.x, t = threadIdx.x;
    int wid = t >> 6, lane = t & 63;
    int h = (lane >> 3) & 1, j = lane & 7;   // lanes >=16 duplicate lanes 0..15
    if (bid < NTOK / 4) {
        int n = bid * 4 + wid;
        if (bid < 16) counts[bid * 256 + t] = 0u;
        const float* row = lat + (size_t)n * DIM;
        int d0 = lane * 4;
        float4 xv = *(const float4*)(row + d0);
        ushort4 bv;
        bv.x = f2bf(xv.x); bv.y = f2bf(xv.y); bv.z = f2bf(xv.z); bv.w = f2bf(xv.w);
        *(ushort4*)(latbf + (size_t)n * DIM + d0) = bv;
        // numpy-exact pairwise norm: 16 accumulators, lanes 0..15 authoritative.
        const float* p = row + h * 128;
        float r = __fmul_rn(p[j], p[j]);
#pragma unroll
        for (int i = 8; i < 128; i += 8)
            r = __fadd_rn(r, __fmul_rn(p[i + j], p[i + j]));
        float v[16];
#pragma unroll
        for (int l = 0; l < 16; ++l) v[l] = __shfl(r, l, 64);
        float h0 = __fadd_rn(__fadd_rn(__fadd_rn(v[0], v[1]), __fadd_rn(v[2], v[3])),
                             __fadd_rn(__fadd_rn(v[4], v[5]), __fadd_rn(v[6], v[7])));
        float h1 = __fadd_rn(__fadd_rn(__fadd_rn(v[8], v[9]), __fadd_rn(v[10], v[11])),
                             __fadd_rn(__fadd_rn(v[12], v[13]), __fadd_rn(v[14], v[15])));
        float nr = fmaxf(sqrtf(__fadd_rn(h0, h1)), 1e-12f);
        if (lane == 0) nrml[n] = nr;
    } else {
        int n = (bid - NTOK / 4) * 4 + wid;
        const float* row = cb + (size_t)n * DIM;
        int d0 = lane * 4;
        float4 xv = *(const float4*)(row + d0);
        // fp32 numpy-exact norm chain + fp64 sq chain
        const float* p = row + h * 128;
        float r = __fmul_rn(p[j], p[j]);
        double ds = 0.0;
#pragma unroll
        for (int i = 8; i < 128; i += 8)
            r = __fadd_rn(r, __fmul_rn(p[i + j], p[i + j]));
#pragma unroll
        for (int i = 0; i < 128; i += 8) { double vv = (double)p[i + j]; ds += vv * vv; }
        float v[16];
#pragma unroll
        for (int l = 0; l < 16; ++l) v[l] = __shfl(r, l, 64);
        float h0 = __fadd_rn(__fadd_rn(__fadd_rn(v[0], v[1]), __fadd_rn(v[2], v[3])),
                             __fadd_rn(__fadd_rn(v[4], v[5]), __fadd_rn(v[6], v[7])));
        float h1 = __fadd_rn(__fadd_rn(__fadd_rn(v[8], v[9]), __fadd_rn(v[10], v[11])),
                             __fadd_rn(__fadd_rn(v[12], v[13]), __fadd_rn(v[14], v[15])));
        float nr = fmaxf(sqrtf(__fadd_rn(h0, h1)), 1e-12f);
        // fp64 sum: butterfly reduce (feeds tolerance-checked pairwise outputs only)
#pragma unroll
        for (int off = 1; off < 16; off <<= 1) ds += __shfl_xor(ds, off, 16);
        if (lane == 0) { nrmc[n] = nr; sq[n] = (float)ds; }
        ushort4 cn, cbv;
        cn.x = f2bf(xv.x / nr); cn.y = f2bf(xv.y / nr);
        cn.z = f2bf(xv.z / nr); cn.w = f2bf(xv.w / nr);
        cbv.x = f2bf(xv.x); cbv.y = f2bf(xv.y); cbv.z = f2bf(xv.z); cbv.w = f2bf(xv.w);
        *(ushort4*)(cnbf + (size_t)n * DIM + d0) = cn;
        *(ushort4*)(cbbf + (size_t)n * DIM + d0) = cbv;
    }
}

// ---- merged GEMM kernel: 256 threads, 4 waves x (32 rows x 128 cols), NO LDS staging ----
// Inputs (~10 MB total) are L2/L3-resident; each wave reads MFMA fragments directly
// from global (per-lane addr = row*512B + kk*2 + quad*16 reproduces the LDS fragment
// layout bit-exactly). No barriers in the main loop -> waves free-run and stagger.
// blocks [0, NSCOB): score tiles -> top-4 keys per (row, 128-colblk)
// blocks [NSCOB, +NPAIRB): codebook pairwise upper-triangle tiles -> sum/min
__global__ __launch_bounds__(256, 3) void gemms(const ushort* __restrict__ latbf,
                                                const ushort* __restrict__ cnbf,
                                                const ushort* __restrict__ cbbf,
                                                const float* __restrict__ sq,
                                                unsigned* __restrict__ keysw,
                                                float* __restrict__ psumw,
                                                unsigned* __restrict__ pminw) {
    __shared__ union {
        unsigned keys[128][68];                         // 34.8 KB score epilogue
        struct { float rs[256]; float rm[256]; } red;   // 2 KB pairwise epilogue
    } sm;
    int tid = threadIdx.x;
    int w = tid >> 6, lane = tid & 63;
    int quad = lane >> 4, l15 = lane & 15;
    bool isScore = blockIdx.x < NSCOB;
    int rowBase, colBase, tri = 0, cbk = 0;
    const ushort *gA, *gB;
    if (isScore) {
        cbk = blockIdx.x & (NCB - 1);
        rowBase = (blockIdx.x >> 5) * 128;
        colBase = cbk * 128;
        gA = latbf; gB = cnbf;
    } else {
        tri = blockIdx.x - NSCOB;
        int a = (int)((sqrtf(8.f * tri + 1.f) - 1.f) * 0.5f);
        while ((a + 1) * (a + 2) / 2 <= tri) ++a;
        while (a * (a + 1) / 2 > tri) --a;
        int b = tri - a * (a + 1) / 2;   // a >= b
        rowBase = b * 128; colBase = a * 128;
        gA = cbbf; gB = cbbf;
    }
    // per-lane fragment row pointers (16 lanes = 16 rows; quad selects k-offset)
    const ushort* pa0 = gA + (size_t)(rowBase + w * 32 + l15) * DIM;
    const ushort* pa1 = pa0 + (size_t)16 * DIM;
    const ushort* pb[8];
#pragma unroll
    for (int nt = 0; nt < 8; ++nt)
        pb[nt] = gB + (size_t)(colBase + nt * 16 + l15) * DIM;

    floatx4 acc[2][8];
#pragma unroll
    for (int m = 0; m < 2; ++m)
#pragma unroll
        for (int n = 0; n < 8; ++n) acc[m][n] = (floatx4){0.f, 0.f, 0.f, 0.f};

    // K loop: same 32-wide K-chunk sequence as the staged version (bit-exact acc).
#pragma unroll 2
    for (int kk = 0; kk < DIM; kk += 32) {
        int off = kk + quad * 8;
        shortx8 a0 = *(const shortx8*)(pa0 + off);
        shortx8 a1 = *(const shortx8*)(pa1 + off);
#pragma unroll
        for (int nt = 0; nt < 8; ++nt) {
            shortx8 bv = *(const shortx8*)(pb[nt] + off);
            acc[0][nt] = __builtin_amdgcn_mfma_f32_16x16x32_bf16(a0, bv, acc[0][nt], 0, 0, 0);
            acc[1][nt] = __builtin_amdgcn_mfma_f32_16x16x32_bf16(a1, bv, acc[1][nt], 0, 0, 0);
        }
    }
    if (isScore) {
        // key = (fmax(score,0) bits, top 19) | sign-tag | colp.  Negatives collapse
        // to +0.0 keys: they can never sit within DELTA of the (positive) row max,
        // and a spurious candidate would lose the exact fp64 re-score anyway.
        unsigned colp2[8];
#pragma unroll
        for (int nt = 0; nt < 8; ++nt)
            colp2[nt] = 0x80000000u | (4095u - (unsigned)(colBase + nt * 16 + l15));
#pragma unroll
        for (int mt = 0; mt < 2; ++mt)
#pragma unroll
            for (int reg = 0; reg < 4; ++reg) {
                unsigned b1 = 0u, b2 = 0u;
#pragma unroll
                for (int nt = 0; nt < 8; ++nt) {
                    unsigned key = (__float_as_uint(fmaxf(acc[mt][nt][reg], 0.f)) & 0x7FFFF000u)
                                   | colp2[nt];
                    unsigned lo = min(key, b1);
                    b1 = max(key, b1);
                    b2 = max(lo, b2);
                }
                int row = w * 32 + mt * 16 + quad * 4 + reg;
                uint2 kv; kv.x = b1; kv.y = b2;
                *(uint2*)&sm.keys[row][l15 * 2] = kv;
            }
        __syncthreads();
        if (tid < 128) {
            // per row: 32 keys -> top-4
            int row = tid;
            unsigned a0 = 0, a1 = 0, a2 = 0, a3 = 0;
#pragma unroll
            for (int j2 = 0; j2 < 8; ++j2) {
                uint4 v4 = *(const uint4*)&sm.keys[row][j2 * 4];
                unsigned vs[4] = {v4.x, v4.y, v4.z, v4.w};
#pragma unroll
                for (int q = 0; q < 4; ++q) {
                    unsigned v = vs[q];
                    unsigned n0 = min(v, a0); a0 = max(v, a0);
                    unsigned n1 = min(n0, a1); a1 = max(n0, a1);
                    unsigned n2 = min(n1, a2); a2 = max(n1, a2);
                    a3 = max(n2, a3);
                }
            }
            size_t base = (size_t)(rowBase + row) * NKROW + (size_t)cbk * NKEY;
            uint4 o; o.x = a0; o.y = a1; o.z = a2; o.w = a3;
            *(uint4*)&keysw[base] = o;
        }
    } else {
        float lsum = 0.f, lmin = INFINITY;
#pragma unroll
        for (int mt = 0; mt < 2; ++mt)
#pragma unroll
            for (int reg = 0; reg < 4; ++reg) {
                int i = rowBase + w * 32 + mt * 16 + quad * 4 + reg;
                float sqi = sq[i];
#pragma unroll
                for (int nt = 0; nt < 8; ++nt) {
                    int j2 = colBase + nt * 16 + l15;
                    float d2 = sqi + sq[j2] - 2.0f * acc[mt][nt][reg];
                    float d = sqrtf(fmaxf(d2, 0.0f));
                    bool use = i < j2;
                    lsum += use ? d : 0.f;
                    lmin = fminf(lmin, use ? d : INFINITY);
                }
            }
        sm.red.rs[tid] = lsum; sm.red.rm[tid] = lmin; __syncthreads();
        for (int s = 128; s > 0; s >>= 1) {
            if (tid < s) {
                sm.red.rs[tid] += sm.red.rs[tid + s];
                sm.red.rm[tid] = fminf(sm.red.rm[tid], sm.red.rm[tid + s]);
            }
            __syncthreads();
        }
        if (tid == 0) { psumw[tri] = sm.red.rs[0]; pminw[tri] = f2ord(sm.red.rm[0]); }
    }
}

// ---- wave-per-row argmax resolve + fused quantized gather/mse ----
__global__ __launch_bounds__(256) void argmax_resolve(const float* __restrict__ lat,
                                                      const float* __restrict__ cb,
                                                      const float* __restrict__ nrml,
                                                      const float* __restrict__ nrmc,
                                                      const unsigned* __restrict__ keysw,
                                                      float* __restrict__ outidx,
                                                      float* __restrict__ outq,
                                                      unsigned* __restrict__ counts,
                                                      float* __restrict__ selw,
                                                      float* __restrict__ msew) {
    __shared__ int scand[4][MAXC];
    __shared__ double sc64[4][MAXC];
    int wid = threadIdx.x >> 6, lane = threadIdx.x & 63;
    int n = blockIdx.x * 4 + wid;
    const unsigned* kr = keysw + (size_t)n * NKROW;
    uint2 kv = *(const uint2*)(kr + lane * 2);
    unsigned m = max(kv.x, kv.y);
#pragma unroll
    for (int off = 1; off < 64; off <<= 1) {
        unsigned o = __shfl_xor(m, off, 64);
        m = max(m, o);
    }
    float v1 = ord2f(m & 0xFFFFF000u);
    float thresh = v1 - DELTA;
    bool p0 = ord2f(kv.x & 0xFFFFF000u) >= thresh;
    bool p1 = ord2f(kv.y & 0xFFFFF000u) >= thresh;
    ull b0 = __ballot(p0), b1 = __ballot(p1);
    int below0 = __builtin_amdgcn_mbcnt_hi((unsigned)(b0 >> 32),
                 __builtin_amdgcn_mbcnt_lo((unsigned)b0, 0));
    int below1 = __builtin_amdgcn_mbcnt_hi((unsigned)(b1 >> 32),
                 __builtin_amdgcn_mbcnt_lo((unsigned)b1, 0));
    int base1 = __popcll(b0);
    int nc = base1 + __popcll(b1);
    if (p0 && below0 < MAXC)
        scand[wid][below0] = 4095 - (int)(kv.x & 0xFFFu);
    if (p1 && base1 + below1 < MAXC)
        scand[wid][base1 + below1] = 4095 - (int)(kv.y & 0xFFFu);
    nc = nc < MAXC ? nc : MAXC;
    __threadfence_block();
    float nx = nrml[n];
    int d0 = lane * 4;
    float4 xv = *(const float4*)(lat + (size_t)n * DIM + d0);
    int idx; float selcos;
    if (nc <= 1) {
        idx = 4095 - (int)(m & 0xFFFu);
        selcos = v1 / nx;
    } else {
        float la0 = xv.x / nx, la1 = xv.y / nx, la2 = xv.z / nx, la3 = xv.w / nx;
        for (int c = 0; c < nc; ++c) {
            int k = scand[wid][c];
            float nk = nrmc[k];
            float4 cv = *(const float4*)(cb + (size_t)k * DIM + d0);
            double part = (double)(cv.x / nk) * la0 + (double)(cv.y / nk) * la1 +
                          (double)(cv.z / nk) * la2 + (double)(cv.w / nk) * la3;
#pragma unroll
            for (int off = 1; off < 64; off <<= 1) part += __shfl_xor(part, off, 64);
            if (lane == 0) sc64[wid][c] = part;
        }
        __threadfence_block();
        double best64 = -1e300;
        for (int c = 0; c < nc; ++c) best64 = fmax(best64, sc64[wid][c]);
        int nrisk = 0;
        for (int c = 0; c < nc; ++c) if (sc64[wid][c] >= best64 - GTIE) ++nrisk;
        if (nrisk == 1) {
            idx = 0x7FFFFFFF; selcos = 0.f;
            for (int c = 0; c < nc; ++c)
                if (sc64[wid][c] >= best64 - GTIE) { idx = scand[wid][c]; selcos = (float)sc64[wid][c]; }
        } else {
            // rare: bit-exact np fp32 chains, one candidate per lane (R4 semantics)
            ull keyf = 0ull, keym = 0ull;
            if (lane < nc && sc64[wid][lane] >= best64 - GTIE) {
                int k = scand[wid][lane];
                const float* cr = cb + (size_t)k * DIM;
                const float* x = lat + (size_t)n * DIM;
                float nk = nrmc[k];
                float af = 0.f, am = 0.f;
                for (int d = 0; d < DIM; ++d) {
                    float la = x[d] / nx;
                    float cv = cr[d] / nk;
                    af = fmaf(la, cv, af);
                    am = __fadd_rn(am, __fmul_rn(la, cv));
                }
                float df = __fsub_rn(2.0f, __fmul_rn(2.0f, af));
                float dm = __fsub_rn(2.0f, __fmul_rn(2.0f, am));
                keyf = ((ull)(0xFFFFFFFFu - f2ord(df)) << 32) | (ull)(0xFFFFFFFFu - (unsigned)k);
                keym = ((ull)(0xFFFFFFFFu - f2ord(dm)) << 32) | (ull)(0xFFFFFFFFu - (unsigned)k);
            }
#pragma unroll
            for (int off = 1; off < 64; off <<= 1) {
                ull of = __shfl_xor(keyf, off, 64);
                ull om = __shfl_xor(keym, off, 64);
                keyf = of > keyf ? of : keyf;
                keym = om > keym ? om : keym;
            }
            int colf = (int)(0xFFFFFFFFu - (unsigned)(keyf & 0xFFFFFFFFull));
            int colm = (int)(0xFFFFFFFFu - (unsigned)(keym & 0xFFFFFFFFull));
            idx = colf < colm ? colf : colm;
            selcos = 0.f;
            for (int c = 0; c < nc; ++c)
                if (scand[wid][c] == idx) selcos = (float)sc64[wid][c];
        }
    }
    // fused gather: idx is wave-uniform on every path
    float4 qv = *(const float4*)(cb + (size_t)idx * DIM + d0);
    *(float4*)(outq + (size_t)n * DIM + d0) = qv;
    float dx = xv.x - qv.x, dy = xv.y - qv.y, dz = xv.z - qv.z, dw = xv.w - qv.w;
    float msep = fmaf(dx, dx, fmaf(dy, dy, fmaf(dz, dz, dw * dw)));
#pragma unroll
    for (int off = 1; off < 64; off <<= 1) msep += __shfl_xor(msep, off, 64);
    if (lane == 0) {
        outidx[n] = (float)idx;
        atomicAdd(&counts[idx], 1u);
        selw[n] = selcos;
        msew[n] = msep;
    }
}

// ---- scalars: reduce all partial arrays ----
__global__ void finalize(const unsigned* __restrict__ counts,
                         const float* __restrict__ selw,
                         const float* __restrict__ msew,
                         const float* __restrict__ psumw,
                         const unsigned* __restrict__ pminw,
                         float* __restrict__ outs) {
    int t = threadIdx.x;
    __shared__ float red[256];
    float h = 0.f;
    for (int k = t; k < KCB; k += 256) {
        float p = (float)counts[k] * (1.0f / (float)NTOK);
        h += p * logf(p + 1e-10f);
    }
    red[t] = h; __syncthreads();
    for (int s = 128; s > 0; s >>= 1) { if (t < s) red[t] += red[t + s]; __syncthreads(); }
    float entNeg = red[0];
    __syncthreads();
    float ssel = 0.f;
    for (int k = t; k < NTOK; k += 256) ssel += selw[k];
    red[t] = ssel; __syncthreads();
    for (int s = 128; s > 0; s >>= 1) { if (t < s) red[t] += red[t + s]; __syncthreads(); }
    float selSum = red[0];
    __syncthreads();
    float sm = 0.f;
    for (int k = t; k < NTOK; k += 256) sm += msew[k];
    red[t] = sm; __syncthreads();
    for (int s = 128; s > 0; s >>= 1) { if (t < s) red[t] += red[t + s]; __syncthreads(); }
    float mseSum = red[0];
    __syncthreads();
    float ps = 0.f;
    for (int k = t; k < NPAIRB; k += 256) ps += psumw[k];
    red[t] = ps; __syncthreads();
    for (int s = 128; s > 0; s >>= 1) { if (t < s) red[t] += red[t + s]; __syncthreads(); }
    float pairSum = red[0];
    __syncthreads();
    unsigned pm = 0xFFFFFFFFu;
    for (int k = t; k < NPAIRB; k += 256) pm = min(pm, pminw[k]);
    ((unsigned*)red)[t] = pm; __syncthreads();
    for (int s = 128; s > 0; s >>= 1) {
        if (t < s) ((unsigned*)red)[t] = min(((unsigned*)red)[t], ((unsigned*)red)[t + s]);
        __syncthreads();
    }
    unsigned pairMin = ((unsigned*)red)[0];
    if (t == 0) {
        float mse = mseSum / (float)(NTOK * DIM);
        outs[0] = 0.25f * mse;
        outs[1] = mse;
        outs[2] = expf(-entNeg);
        outs[3] = selSum / (float)NTOK;
        outs[4] = pairSum * 2.0f / ((float)KCB * (float)(KCB - 1));
        outs[5] = ord2f(pairMin);
    }
}

extern "C" void kernel_launch(void* const* d_in, const int* in_sizes, int n_in,
                              void* d_out, int out_size, void* d_ws, size_t ws_size,
                              hipStream_t stream) {
    const float* latent = (const float*)d_in[0];    // [8192,256]
    const float* codebook = (const float*)d_in[1];  // [4096,256]
    float* out = (float*)d_out;
    float* outq = out;
    float* outidx = out + (size_t)NTOK * DIM;
    float* outs = outidx + NTOK;

    unsigned* keysw = (unsigned*)d_ws;                        // 128*8192 u32 = 4 MB
    ushort* latbf = (ushort*)(keysw + (size_t)NKROW * NTOK);  // 4 MB
    ushort* cnbf = latbf + (size_t)NTOK * DIM;                // 2 MB
    ushort* cbbf = cnbf + (size_t)KCB * DIM;                  // 2 MB
    float* nrml = (float*)(cbbf + (size_t)KCB * DIM);         // 8192
    float* nrmc = nrml + NTOK;                                // 4096
    float* sq = nrmc + KCB;                                   // 4096
    unsigned* counts = (unsigned*)(sq + KCB);                 // 4096
    float* selw = (float*)(counts + KCB);                     // 8192
    float* msew = selw + NTOK;                                // 8192
    float* psumw = msew + NTOK;                               // 528
    unsigned* pminw = (unsigned*)(psumw + NPAIRB);            // 528

    hipLaunchKernelGGL(prep, dim3(NTOK / 4 + KCB / 4), dim3(256), 0, stream,
                       latent, codebook, nrml, nrmc, latbf, cnbf, cbbf, sq, counts);
    hipLaunchKernelGGL(gemms, dim3(NSCOB + NPAIRB), dim3(256), 0, stream,
                       latbf, cnbf, cbbf, sq, keysw, psumw, pminw);
    hipLaunchKernelGGL(argmax_resolve, dim3(NTOK / 4), dim3(256), 0, stream,
                       latent, codebook, nrml, nrmc, keysw, outidx, outq, counts, selw, msew);
    hipLaunchKernelGGL(finalize, dim3(1), dim3(256), 0, stream, counts, selw, msew, psumw, pminw, outs);
}

// Round 8
// 174.646 us; speedup vs baseline: 1.3331x; 1.3331x over previous
//
#include <hip/hip_runtime.h>
#include <hip/hip_bf16.h>
#include <math.h>

#define NTOK 8192
#define DIM 256
#define KCB 4096
#define NCB (KCB / 128)    // 32 col-blocks in keysw layout
#define NKEY 4             // top-4 kept per (row, col-block)
#define NKROW (NCB * NKEY) // 128 u32 keys per row
#define DELTA 0.08f        // candidate window, raw-dot units (~20 sigma of bf16 noise + quant)
#define GTIE 2e-6          // fp64 cosine gap below which we run the bit-exact np chain
#define MAXC 16
#define NSCOB2 ((NTOK / 256) * (KCB / 256))        // 512 score blocks (256x256)
#define NTRI2 ((KCB / 256) * (KCB / 256 + 1) / 2)  // 136 pairwise blocks (256x256)
#define NPAIRB NTRI2
#define NWG (NSCOB2 + NTRI2)                        // 648 = 8 * 81 (exact)

typedef unsigned long long ull;
typedef unsigned short ushort;
typedef __attribute__((ext_vector_type(8))) short shortx8;   // 8 bf16 (4 VGPRs)
typedef __attribute__((ext_vector_type(4))) float floatx4;
typedef const __attribute__((address_space(1))) void* gas_cp;
typedef __attribute__((address_space(3))) void* las_p;

// ---- float <-> order-preserving u32 ----
__device__ __forceinline__ unsigned f2ord(float f) {
    unsigned u = __float_as_uint(f);
    return (u & 0x80000000u) ? ~u : (u | 0x80000000u);
}
__device__ __forceinline__ float ord2f(unsigned u) {
    unsigned b = (u & 0x80000000u) ? (u & 0x7FFFFFFFu) : ~u;
    return __uint_as_float(b);
}
__device__ __forceinline__ ushort f2bf(float f) {   // RNE fp32->bf16
    unsigned u = __float_as_uint(f);
    unsigned r = u + 0x7FFFu + ((u >> 16) & 1u);
    return (ushort)(r >> 16);
}

// ---- shared memory: double-buffered 256x64 GEMM tiles alias epilogue storage ----
union TileSmem {
    struct { ushort a[256][64]; ushort b[256][64]; } t[2];   // 128 KB
    unsigned keys[256][68];                                  // 69.6 KB (scores epi)
    struct { float rs[512]; float rm[512]; } red;            // 4 KB (pairwise epi)
};

// ---- async stage: each of 8 waves stages 32 rows of A and 32 rows of B ----
// XOR-swizzled 16B chunks; LDS dest linear (gload_lds rule), source pre-swizzled.
// Exactly 8 global_load_lds per wave per call (vmcnt bookkeeping relies on this).
__device__ __forceinline__ void stage_tile8(const ushort* __restrict__ gA,
                                            const ushort* __restrict__ gB,
                                            ushort (*la)[64], ushort (*lb)[64],
                                            int wave, int lane, int kk) {
    int p = lane & 7;
    int rsub = lane >> 3;
    int kc = p ^ rsub;   // rsub < 8
    const ushort* sa = gA + (size_t)(wave * 32 + rsub) * DIM + kk + kc * 8;
    const ushort* sb = gB + (size_t)(wave * 32 + rsub) * DIM + kk + kc * 8;
#pragma unroll
    for (int c = 0; c < 4; ++c) {
        __builtin_amdgcn_global_load_lds((gas_cp)(sa + (size_t)(c * 8) * DIM),
                                         (las_p)&la[wave * 32 + c * 8][0], 16, 0, 0);
        __builtin_amdgcn_global_load_lds((gas_cp)(sb + (size_t)(c * 8) * DIM),
                                         (las_p)&lb[wave * 32 + c * 8][0], 16, 0, 0);
    }
}
__device__ __forceinline__ shortx8 frag_read(const ushort (*lds)[64], int row,
                                             int lc) {
    return *(const shortx8*)&lds[row][(lc ^ (row & 7)) * 8];
}

// ---- fused prep: 4 rows per block, one wave per row ----
// blocks [0, NTOK/4): latent rows; [NTOK/4, NTOK/4 + KCB/4): codebook rows
__global__ __launch_bounds__(256) void prep(const float* __restrict__ lat,
                                            const float* __restrict__ cb,
                                            float* __restrict__ nrml,
                                            float* __restrict__ nrmc,
                                            ushort* __restrict__ latbf,
                                            ushort* __restrict__ cnbf,
                                            ushort* __restrict__ cbbf,
                                            float* __restrict__ sq,
                                            unsigned* __restrict__ counts) {
    int bid = blockIdx.x, t = threadIdx.x;
    int wid = t >> 6, lane = t & 63;
    int h = (lane >> 3) & 1, j = lane & 7;   // lanes >=16 duplicate lanes 0..15
    if (bid < NTOK / 4) {
        int n = bid * 4 + wid;
        if (bid < 16) counts[bid * 256 + t] = 0u;
        const float* row = lat + (size_t)n * DIM;
        int d0 = lane * 4;
        float4 xv = *(const float4*)(row + d0);
        ushort4 bv;
        bv.x = f2bf(xv.x); bv.y = f2bf(xv.y); bv.z = f2bf(xv.z); bv.w = f2bf(xv.w);
        *(ushort4*)(latbf + (size_t)n * DIM + d0) = bv;
        // numpy-exact pairwise norm: 16 accumulators, lanes 0..15 authoritative.
        // Unrolled: loads pipeline; __fadd_rn chain order preserved (bit-exact).
        const float* p = row + h * 128;
        float r = __fmul_rn(p[j], p[j]);
#pragma unroll
        for (int i = 8; i < 128; i += 8)
            r = __fadd_rn(r, __fmul_rn(p[i + j], p[i + j]));
        float v[16];
#pragma unroll
        for (int l = 0; l < 16; ++l) v[l] = __shfl(r, l, 64);
        float h0 = __fadd_rn(__fadd_rn(__fadd_rn(v[0], v[1]), __fadd_rn(v[2], v[3])),
                             __fadd_rn(__fadd_rn(v[4], v[5]), __fadd_rn(v[6], v[7])));
        float h1 = __fadd_rn(__fadd_rn(__fadd_rn(v[8], v[9]), __fadd_rn(v[10], v[11])),
                             __fadd_rn(__fadd_rn(v[12], v[13]), __fadd_rn(v[14], v[15])));
        float nr = fmaxf(sqrtf(__fadd_rn(h0, h1)), 1e-12f);
        if (lane == 0) nrml[n] = nr;
    } else {
        int n = (bid - NTOK / 4) * 4 + wid;
        const float* row = cb + (size_t)n * DIM;
        int d0 = lane * 4;
        float4 xv = *(const float4*)(row + d0);
        // fp32 numpy-exact norm chain + fp64 sq chain
        const float* p = row + h * 128;
        float r = __fmul_rn(p[j], p[j]);
        double ds = 0.0;
#pragma unroll
        for (int i = 8; i < 128; i += 8)
            r = __fadd_rn(r, __fmul_rn(p[i + j], p[i + j]));
#pragma unroll
        for (int i = 0; i < 128; i += 8) { double vv = (double)p[i + j]; ds += vv * vv; }
        float v[16];
#pragma unroll
        for (int l = 0; l < 16; ++l) v[l] = __shfl(r, l, 64);
        float h0 = __fadd_rn(__fadd_rn(__fadd_rn(v[0], v[1]), __fadd_rn(v[2], v[3])),
                             __fadd_rn(__fadd_rn(v[4], v[5]), __fadd_rn(v[6], v[7])));
        float h1 = __fadd_rn(__fadd_rn(__fadd_rn(v[8], v[9]), __fadd_rn(v[10], v[11])),
                             __fadd_rn(__fadd_rn(v[12], v[13]), __fadd_rn(v[14], v[15])));
        float nr = fmaxf(sqrtf(__fadd_rn(h0, h1)), 1e-12f);
        // fp64 sum: butterfly reduce (feeds tolerance-checked pairwise outputs only)
#pragma unroll
        for (int off = 1; off < 16; off <<= 1) ds += __shfl_xor(ds, off, 16);
        if (lane == 0) { nrmc[n] = nr; sq[n] = (float)ds; }
        ushort4 cn, cbv;
        cn.x = f2bf(xv.x / nr); cn.y = f2bf(xv.y / nr);
        cn.z = f2bf(xv.z / nr); cn.w = f2bf(xv.w / nr);
        cbv.x = f2bf(xv.x); cbv.y = f2bf(xv.y); cbv.z = f2bf(xv.z); cbv.w = f2bf(xv.w);
        *(ushort4*)(cnbf + (size_t)n * DIM + d0) = cn;
        *(ushort4*)(cbbf + (size_t)n * DIM + d0) = cbv;
    }
}

// ---- merged GEMM kernel: 512 threads, 8 waves x (64 rows x 128 cols) over 256x256 ----
// Counted-vmcnt pipeline (T4): two K-tiles in flight, never drain to 0 mid-loop.
// T1: bijective XCD swizzle (648 = 8*81 exact) -> each XCD owns 81 contiguous
// tiles sharing A row-panels + the whole cnbf in its private L2.
// blocks [0, NSCOB2): score tiles -> top-4 keys per (row, 128-colblk)
// blocks [NSCOB2, +NTRI2): codebook pairwise upper-triangle tiles -> sum/min
__global__ __launch_bounds__(512, 2) void gemms(const ushort* __restrict__ latbf,
                                                const ushort* __restrict__ cnbf,
                                                const ushort* __restrict__ cbbf,
                                                const float* __restrict__ sq,
                                                unsigned* __restrict__ keysw,
                                                float* __restrict__ psumw,
                                                unsigned* __restrict__ pminw) {
    __shared__ TileSmem sm;
    int tid = threadIdx.x;
    int wave = tid >> 6, lane = tid & 63;
    int quad = lane >> 4, l15 = lane & 15;
    int wr = wave >> 1, wc = wave & 1;   // 4x2 wave grid: each wave 64 rows x 128 cols
    int wg = (blockIdx.x & 7) * (NWG / 8) + (blockIdx.x >> 3);  // bijective XCD swizzle
    bool isScore = wg < NSCOB2;
    int rowBase, colBase, tri = 0, cbk = 0;
    const ushort *gA, *gB;
    if (isScore) {
        cbk = wg & 15;
        int rbk = wg >> 4;
        rowBase = rbk * 256; colBase = cbk * 256;
        gA = latbf + (size_t)rowBase * DIM;
        gB = cnbf + (size_t)colBase * DIM;
    } else {
        tri = wg - NSCOB2;
        int a = (int)((sqrtf(8.f * tri + 1.f) - 1.f) * 0.5f);
        while ((a + 1) * (a + 2) / 2 <= tri) ++a;
        while (a * (a + 1) / 2 > tri) --a;
        int b = tri - a * (a + 1) / 2;   // a >= b
        rowBase = b * 256; colBase = a * 256;
        gA = cbbf + (size_t)rowBase * DIM;
        gB = cbbf + (size_t)colBase * DIM;
    }
    floatx4 acc[4][8];
#pragma unroll
    for (int m = 0; m < 4; ++m)
#pragma unroll
        for (int n = 0; n < 8; ++n) acc[m][n] = (floatx4){0.f, 0.f, 0.f, 0.f};

    // prologue: two tiles in flight
    stage_tile8(gA, gB, sm.t[0].a, sm.t[0].b, wave, lane, 0);
    stage_tile8(gA, gB, sm.t[1].a, sm.t[1].b, wave, lane, 64);
#pragma unroll
    for (int t = 0; t < 4; ++t) {
        int cur = t & 1;
        if (t < 3)
            asm volatile("s_waitcnt vmcnt(8)" ::: "memory");
        else
            asm volatile("s_waitcnt vmcnt(0)" ::: "memory");
        __builtin_amdgcn_s_barrier();
#pragma unroll
        for (int s = 0; s < 2; ++s) {
            shortx8 af[4], bfv[8];
#pragma unroll
            for (int mt = 0; mt < 4; ++mt)
                af[mt] = frag_read(sm.t[cur].a, wr * 64 + mt * 16 + l15, s * 4 + quad);
#pragma unroll
            for (int nt = 0; nt < 8; ++nt)
                bfv[nt] = frag_read(sm.t[cur].b, wc * 128 + nt * 16 + l15, s * 4 + quad);
            __builtin_amdgcn_s_setprio(1);
#pragma unroll
            for (int mt = 0; mt < 4; ++mt)
#pragma unroll
                for (int nt = 0; nt < 8; ++nt)
                    acc[mt][nt] = __builtin_amdgcn_mfma_f32_16x16x32_bf16(
                        af[mt], bfv[nt], acc[mt][nt], 0, 0, 0);
            __builtin_amdgcn_s_setprio(0);
        }
        __builtin_amdgcn_s_barrier();
        if (t < 2)
            stage_tile8(gA, gB, sm.t[cur].a, sm.t[cur].b, wave, lane, (t + 2) * 64);
    }
    __syncthreads();   // tiles dead; reuse LDS for epilogue
    if (isScore) {
        // key = (fmax(score,0) bits, top 19) | sign-tag | colp.  Negatives collapse
        // to +0.0 keys: they can never sit within DELTA of the (positive) row max,
        // and a spurious candidate would lose the exact fp64 re-score anyway.
        unsigned colp2[8];
#pragma unroll
        for (int nt = 0; nt < 8; ++nt)
            colp2[nt] = 0x80000000u | (4095u - (unsigned)(colBase + wc * 128 + nt * 16 + l15));
#pragma unroll
        for (int mt = 0; mt < 4; ++mt)
#pragma unroll
            for (int reg = 0; reg < 4; ++reg) {
                unsigned b1 = 0u, b2 = 0u;
#pragma unroll
                for (int nt = 0; nt < 8; ++nt) {
                    unsigned key = (__float_as_uint(fmaxf(acc[mt][nt][reg], 0.f)) & 0x7FFFF000u)
                                   | colp2[nt];
                    unsigned lo = min(key, b1);
                    b1 = max(key, b1);
                    b2 = max(lo, b2);
                }
                int row = wr * 64 + mt * 16 + quad * 4 + reg;
                uint2 kv; kv.x = b1; kv.y = b2;
                *(uint2*)&sm.keys[row][(wc * 16 + l15) * 2] = kv;
            }
        __syncthreads();
        {
            // per (row, 128-col half): 32 keys; one thread folds each -> top-4
            int prow = tid >> 1, hh = tid & 1;
            unsigned a0 = 0, a1 = 0, a2 = 0, a3 = 0;
#pragma unroll
            for (int j2 = 0; j2 < 8; ++j2) {
                uint4 v4 = *(const uint4*)&sm.keys[prow][hh * 32 + j2 * 4];
                unsigned vs[4] = {v4.x, v4.y, v4.z, v4.w};
#pragma unroll
                for (int q = 0; q < 4; ++q) {
                    unsigned v = vs[q];
                    unsigned n0 = min(v, a0); a0 = max(v, a0);
                    unsigned n1 = min(n0, a1); a1 = max(n0, a1);
                    unsigned n2 = min(n1, a2); a2 = max(n1, a2);
                    a3 = max(n2, a3);
                }
            }
            size_t base = (size_t)(rowBase + prow) * NKROW + (size_t)(cbk * 2 + hh) * NKEY;
            uint4 o; o.x = a0; o.y = a1; o.z = a2; o.w = a3;
            *(uint4*)&keysw[base] = o;
        }
    } else {
        float lsum = 0.f, lmin = INFINITY;
#pragma unroll
        for (int mt = 0; mt < 4; ++mt)
#pragma unroll
            for (int reg = 0; reg < 4; ++reg) {
                int i = rowBase + wr * 64 + mt * 16 + quad * 4 + reg;
                float sqi = sq[i];
#pragma unroll
                for (int nt = 0; nt < 8; ++nt) {
                    int j2 = colBase + wc * 128 + nt * 16 + l15;
                    float d2 = sqi + sq[j2] - 2.0f * acc[mt][nt][reg];
                    float d = sqrtf(fmaxf(d2, 0.0f));
                    bool use = i < j2;
                    lsum += use ? d : 0.f;
                    lmin = fminf(lmin, use ? d : INFINITY);
                }
            }
        sm.red.rs[tid] = lsum; sm.red.rm[tid] = lmin; __syncthreads();
        for (int s = 256; s > 0; s >>= 1) {
            if (tid < s) {
                sm.red.rs[tid] += sm.red.rs[tid + s];
                sm.red.rm[tid] = fminf(sm.red.rm[tid], sm.red.rm[tid + s]);
            }
            __syncthreads();
        }
        if (tid == 0) { psumw[tri] = sm.red.rs[0]; pminw[tri] = f2ord(sm.red.rm[0]); }
    }
}

// ---- wave-per-row argmax resolve + fused quantized gather/mse ----
__global__ __launch_bounds__(256) void argmax_resolve(const float* __restrict__ lat,
                                                      const float* __restrict__ cb,
                                                      const float* __restrict__ nrml,
                                                      const float* __restrict__ nrmc,
                                                      const unsigned* __restrict__ keysw,
                                                      float* __restrict__ outidx,
                                                      float* __restrict__ outq,
                                                      unsigned* __restrict__ counts,
                                                      float* __restrict__ selw,
                                                      float* __restrict__ msew) {
    __shared__ int scand[4][MAXC];
    __shared__ double sc64[4][MAXC];
    int wid = threadIdx.x >> 6, lane = threadIdx.x & 63;
    int n = blockIdx.x * 4 + wid;
    const unsigned* kr = keysw + (size_t)n * NKROW;
    uint2 kv = *(const uint2*)(kr + lane * 2);
    unsigned m = max(kv.x, kv.y);
#pragma unroll
    for (int off = 1; off < 64; off <<= 1) {
        unsigned o = __shfl_xor(m, off, 64);
        m = max(m, o);
    }
    float v1 = ord2f(m & 0xFFFFF000u);
    float thresh = v1 - DELTA;
    bool p0 = ord2f(kv.x & 0xFFFFF000u) >= thresh;
    bool p1 = ord2f(kv.y & 0xFFFFF000u) >= thresh;
    ull b0 = __ballot(p0), b1 = __ballot(p1);
    int below0 = __builtin_amdgcn_mbcnt_hi((unsigned)(b0 >> 32),
                 __builtin_amdgcn_mbcnt_lo((unsigned)b0, 0));
    int below1 = __builtin_amdgcn_mbcnt_hi((unsigned)(b1 >> 32),
                 __builtin_amdgcn_mbcnt_lo((unsigned)b1, 0));
    int base1 = __popcll(b0);
    int nc = base1 + __popcll(b1);
    if (p0 && below0 < MAXC)
        scand[wid][below0] = 4095 - (int)(kv.x & 0xFFFu);
    if (p1 && base1 + below1 < MAXC)
        scand[wid][base1 + below1] = 4095 - (int)(kv.y & 0xFFFu);
    nc = nc < MAXC ? nc : MAXC;
    __threadfence_block();
    float nx = nrml[n];
    int d0 = lane * 4;
    float4 xv = *(const float4*)(lat + (size_t)n * DIM + d0);
    int idx; float selcos;
    if (nc <= 1) {
        idx = 4095 - (int)(m & 0xFFFu);
        selcos = v1 / nx;
    } else {
        float la0 = xv.x / nx, la1 = xv.y / nx, la2 = xv.z / nx, la3 = xv.w / nx;
        for (int c = 0; c < nc; ++c) {
            int k = scand[wid][c];
            float nk = nrmc[k];
            float4 cv = *(const float4*)(cb + (size_t)k * DIM + d0);
            double part = (double)(cv.x / nk) * la0 + (double)(cv.y / nk) * la1 +
                          (double)(cv.z / nk) * la2 + (double)(cv.w / nk) * la3;
#pragma unroll
            for (int off = 1; off < 64; off <<= 1) part += __shfl_xor(part, off, 64);
            if (lane == 0) sc64[wid][c] = part;
        }
        __threadfence_block();
        double best64 = -1e300;
        for (int c = 0; c < nc; ++c) best64 = fmax(best64, sc64[wid][c]);
        int nrisk = 0;
        for (int c = 0; c < nc; ++c) if (sc64[wid][c] >= best64 - GTIE) ++nrisk;
        if (nrisk == 1) {
            idx = 0x7FFFFFFF; selcos = 0.f;
            for (int c = 0; c < nc; ++c)
                if (sc64[wid][c] >= best64 - GTIE) { idx = scand[wid][c]; selcos = (float)sc64[wid][c]; }
        } else {
            // rare: bit-exact np fp32 chains, one candidate per lane (R4 semantics)
            ull keyf = 0ull, keym = 0ull;
            if (lane < nc && sc64[wid][lane] >= best64 - GTIE) {
                int k = scand[wid][lane];
                const float* cr = cb + (size_t)k * DIM;
                const float* x = lat + (size_t)n * DIM;
                float nk = nrmc[k];
                float af = 0.f, am = 0.f;
                for (int d = 0; d < DIM; ++d) {
                    float la = x[d] / nx;
                    float cv = cr[d] / nk;
                    af = fmaf(la, cv, af);
                    am = __fadd_rn(am, __fmul_rn(la, cv));
                }
                float df = __fsub_rn(2.0f, __fmul_rn(2.0f, af));
                float dm = __fsub_rn(2.0f, __fmul_rn(2.0f, am));
                keyf = ((ull)(0xFFFFFFFFu - f2ord(df)) << 32) | (ull)(0xFFFFFFFFu - (unsigned)k);
                keym = ((ull)(0xFFFFFFFFu - f2ord(dm)) << 32) | (ull)(0xFFFFFFFFu - (unsigned)k);
            }
#pragma unroll
            for (int off = 1; off < 64; off <<= 1) {
                ull of = __shfl_xor(keyf, off, 64);
                ull om = __shfl_xor(keym, off, 64);
                keyf = of > keyf ? of : keyf;
                keym = om > keym ? om : keym;
            }
            int colf = (int)(0xFFFFFFFFu - (unsigned)(keyf & 0xFFFFFFFFull));
            int colm = (int)(0xFFFFFFFFu - (unsigned)(keym & 0xFFFFFFFFull));
            idx = colf < colm ? colf : colm;
            selcos = 0.f;
            for (int c = 0; c < nc; ++c)
                if (scand[wid][c] == idx) selcos = (float)sc64[wid][c];
        }
    }
    // fused gather: idx is wave-uniform on every path
    float4 qv = *(const float4*)(cb + (size_t)idx * DIM + d0);
    *(float4*)(outq + (size_t)n * DIM + d0) = qv;
    float dx = xv.x - qv.x, dy = xv.y - qv.y, dz = xv.z - qv.z, dw = xv.w - qv.w;
    float msep = fmaf(dx, dx, fmaf(dy, dy, fmaf(dz, dz, dw * dw)));
#pragma unroll
    for (int off = 1; off < 64; off <<= 1) msep += __shfl_xor(msep, off, 64);
    if (lane == 0) {
        outidx[n] = (float)idx;
        atomicAdd(&counts[idx], 1u);
        selw[n] = selcos;
        msew[n] = msep;
    }
}

// ---- scalars: reduce all partial arrays ----
__global__ void finalize(const unsigned* __restrict__ counts,
                         const float* __restrict__ selw,
                         const float* __restrict__ msew,
                         const float* __restrict__ psumw,
                         const unsigned* __restrict__ pminw,
                         float* __restrict__ outs) {
    int t = threadIdx.x;
    __shared__ float red[256];
    float h = 0.f;
    for (int k = t; k < KCB; k += 256) {
        float p = (float)counts[k] * (1.0f / (float)NTOK);
        h += p * logf(p + 1e-10f);
    }
    red[t] = h; __syncthreads();
    for (int s = 128; s > 0; s >>= 1) { if (t < s) red[t] += red[t + s]; __syncthreads(); }
    float entNeg = red[0];
    __syncthreads();
    float ssel = 0.f;
    for (int k = t; k < NTOK; k += 256) ssel += selw[k];
    red[t] = ssel; __syncthreads();
    for (int s = 128; s > 0; s >>= 1) { if (t < s) red[t] += red[t + s]; __syncthreads(); }
    float selSum = red[0];
    __syncthreads();
    float sm = 0.f;
    for (int k = t; k < NTOK; k += 256) sm += msew[k];
    red[t] = sm; __syncthreads();
    for (int s = 128; s > 0; s >>= 1) { if (t < s) red[t] += red[t + s]; __syncthreads(); }
    float mseSum = red[0];
    __syncthreads();
    float ps = 0.f;
    for (int k = t; k < NPAIRB; k += 256) ps += psumw[k];
    red[t] = ps; __syncthreads();
    for (int s = 128; s > 0; s >>= 1) { if (t < s) red[t] += red[t + s]; __syncthreads(); }
    float pairSum = red[0];
    __syncthreads();
    unsigned pm = 0xFFFFFFFFu;
    for (int k = t; k < NPAIRB; k += 256) pm = min(pm, pminw[k]);
    ((unsigned*)red)[t] = pm; __syncthreads();
    for (int s = 128; s > 0; s >>= 1) {
        if (t < s) ((unsigned*)red)[t] = min(((unsigned*)red)[t], ((unsigned*)red)[t + s]);
        __syncthreads();
    }
    unsigned pairMin = ((unsigned*)red)[0];
    if (t == 0) {
        float mse = mseSum / (float)(NTOK * DIM);
        outs[0] = 0.25f * mse;
        outs[1] = mse;
        outs[2] = expf(-entNeg);
        outs[3] = selSum / (float)NTOK;
        outs[4] = pairSum * 2.0f / ((float)KCB * (float)(KCB - 1));
        outs[5] = ord2f(pairMin);
    }
}

extern "C" void kernel_launch(void* const* d_in, const int* in_sizes, int n_in,
                              void* d_out, int out_size, void* d_ws, size_t ws_size,
                              hipStream_t stream) {
    const float* latent = (const float*)d_in[0];    // [8192,256]
    const float* codebook = (const float*)d_in[1];  // [4096,256]
    float* out = (float*)d_out;
    float* outq = out;
    float* outidx = out + (size_t)NTOK * DIM;
    float* outs = outidx + NTOK;

    unsigned* keysw = (unsigned*)d_ws;                        // 128*8192 u32 = 4 MB
    ushort* latbf = (ushort*)(keysw + (size_t)NKROW * NTOK);  // 4 MB
    ushort* cnbf = latbf + (size_t)NTOK * DIM;                // 2 MB
    ushort* cbbf = cnbf + (size_t)KCB * DIM;                  // 2 MB
    float* nrml = (float*)(cbbf + (size_t)KCB * DIM);         // 8192
    float* nrmc = nrml + NTOK;                                // 4096
    float* sq = nrmc + KCB;                                   // 4096
    unsigned* counts = (unsigned*)(sq + KCB);                 // 4096
    float* selw = (float*)(counts + KCB);                     // 8192
    float* msew = selw + NTOK;                                // 8192
    float* psumw = msew + NTOK;                               // 528 (only NPAIRB=136 used)
    unsigned* pminw = (unsigned*)(psumw + 528);               // 528 (only NPAIRB=136 used)

    hipLaunchKernelGGL(prep, dim3(NTOK / 4 + KCB / 4), dim3(256), 0, stream,
                       latent, codebook, nrml, nrmc, latbf, cnbf, cbbf, sq, counts);
    hipLaunchKernelGGL(gemms, dim3(NWG), dim3(512), 0, stream,
                       latbf, cnbf, cbbf, sq, keysw, psumw, pminw);
    hipLaunchKernelGGL(argmax_resolve, dim3(NTOK / 4), dim3(256), 0, stream,
                       latent, codebook, nrml, nrmc, keysw, outidx, outq, counts, selw, msew);
    hipLaunchKernelGGL(finalize, dim3(1), dim3(256), 0, stream, counts, selw, msew, psumw, pminw, outs);
}

// Round 9
// 163.568 us; speedup vs baseline: 1.4234x; 1.0677x over previous
//
#include <hip/hip_runtime.h>
#include <hip/hip_bf16.h>
#include <math.h>

#define NTOK 8192
#define DIM 256
#define KCB 4096
#define NCB (KCB / 128)    // 32 col-blocks in keysw layout
#define NKEY 4             // top-4 kept per (row, col-block)
#define NKROW (NCB * NKEY) // 128 u32 keys per row
#define DELTA 0.08f        // candidate window, raw-dot units (~20 sigma of bf16 noise + quant)
#define GTIE 2e-6          // fp64 cosine gap below which we run the bit-exact np chain
#define MAXC 16
#define NSCOB2 ((NTOK / 256) * (KCB / 256))        // 512 score blocks (256x256)
#define NTRI2 ((KCB / 256) * (KCB / 256 + 1) / 2)  // 136 pairwise blocks (256x256)
#define NPAIRB NTRI2

typedef unsigned long long ull;
typedef unsigned short ushort;
typedef __attribute__((ext_vector_type(8))) short shortx8;   // 8 bf16 (4 VGPRs)
typedef __attribute__((ext_vector_type(4))) float floatx4;
typedef const __attribute__((address_space(1))) void* gas_cp;
typedef __attribute__((address_space(3))) void* las_p;

// ---- float <-> order-preserving u32 ----
__device__ __forceinline__ unsigned f2ord(float f) {
    unsigned u = __float_as_uint(f);
    return (u & 0x80000000u) ? ~u : (u | 0x80000000u);
}
__device__ __forceinline__ float ord2f(unsigned u) {
    unsigned b = (u & 0x80000000u) ? (u & 0x7FFFFFFFu) : ~u;
    return __uint_as_float(b);
}
__device__ __forceinline__ ushort f2bf(float f) {   // RNE fp32->bf16
    unsigned u = __float_as_uint(f);
    unsigned r = u + 0x7FFFu + ((u >> 16) & 1u);
    return (ushort)(r >> 16);
}
// median-of-3 u32 (single VOP3 on gfx950); med3(old_top, old_second, key) == new
// second-max when old_top >= old_second — 1 instr replaces min+max.
__device__ __forceinline__ unsigned med3u(unsigned a, unsigned b, unsigned c) {
    unsigned d;
    asm("v_med3_u32 %0, %1, %2, %3" : "=v"(d) : "v"(a), "v"(b), "v"(c));
    return d;
}

// ---- shared memory: double-buffered 256x64 GEMM tiles alias epilogue storage ----
union TileSmem {
    struct { ushort a[256][64]; ushort b[256][64]; } t[2];   // 128 KB
    unsigned keys[256][68];                                  // 69.6 KB (scores epi)
    struct { float rs[512]; float rm[512]; } red;            // 4 KB (pairwise epi)
};

// ---- async stage: each of 8 waves stages 32 rows of A and 32 rows of B ----
// XOR-swizzled 16B chunks; LDS dest linear (gload_lds rule), source pre-swizzled.
// Exactly 8 global_load_lds per wave per call (vmcnt bookkeeping relies on this).
__device__ __forceinline__ void stage_tile8(const ushort* __restrict__ gA,
                                            const ushort* __restrict__ gB,
                                            ushort (*la)[64], ushort (*lb)[64],
                                            int wave, int lane, int kk) {
    int p = lane & 7;
    int rsub = lane >> 3;
    int kc = p ^ rsub;   // rsub < 8
    const ushort* sa = gA + (size_t)(wave * 32 + rsub) * DIM + kk + kc * 8;
    const ushort* sb = gB + (size_t)(wave * 32 + rsub) * DIM + kk + kc * 8;
#pragma unroll
    for (int c = 0; c < 4; ++c) {
        __builtin_amdgcn_global_load_lds((gas_cp)(sa + (size_t)(c * 8) * DIM),
                                         (las_p)&la[wave * 32 + c * 8][0], 16, 0, 0);
        __builtin_amdgcn_global_load_lds((gas_cp)(sb + (size_t)(c * 8) * DIM),
                                         (las_p)&lb[wave * 32 + c * 8][0], 16, 0, 0);
    }
}
__device__ __forceinline__ shortx8 frag_read(const ushort (*lds)[64], int row,
                                             int lc) {
    return *(const shortx8*)&lds[row][(lc ^ (row & 7)) * 8];
}

// ---- fused prep: 4 rows per block, one wave per row ----
// blocks [0, NTOK/4): latent rows; [NTOK/4, NTOK/4 + KCB/4): codebook rows
__global__ __launch_bounds__(256) void prep(const float* __restrict__ lat,
                                            const float* __restrict__ cb,
                                            float* __restrict__ nrml,
                                            float* __restrict__ nrmc,
                                            ushort* __restrict__ latbf,
                                            ushort* __restrict__ cnbf,
                                            ushort* __restrict__ cbbf,
                                            float* __restrict__ sq,
                                            unsigned* __restrict__ counts) {
    int bid = blockIdx.x, t = threadIdx.x;
    int wid = t >> 6, lane = t & 63;
    int h = (lane >> 3) & 1, j = lane & 7;   // lanes >=16 duplicate lanes 0..15
    if (bid < NTOK / 4) {
        int n = bid * 4 + wid;
        if (bid < 16) counts[bid * 256 + t] = 0u;
        const float* row = lat + (size_t)n * DIM;
        int d0 = lane * 4;
        float4 xv = *(const float4*)(row + d0);
        ushort4 bv;
        bv.x = f2bf(xv.x); bv.y = f2bf(xv.y); bv.z = f2bf(xv.z); bv.w = f2bf(xv.w);
        *(ushort4*)(latbf + (size_t)n * DIM + d0) = bv;
        // numpy-exact pairwise norm: 16 accumulators, lanes 0..15 authoritative.
        // Unrolled: loads pipeline; __fadd_rn chain order preserved (bit-exact).
        const float* p = row + h * 128;
        float r = __fmul_rn(p[j], p[j]);
#pragma unroll
        for (int i = 8; i < 128; i += 8)
            r = __fadd_rn(r, __fmul_rn(p[i + j], p[i + j]));
        float v[16];
#pragma unroll
        for (int l = 0; l < 16; ++l) v[l] = __shfl(r, l, 64);
        float h0 = __fadd_rn(__fadd_rn(__fadd_rn(v[0], v[1]), __fadd_rn(v[2], v[3])),
                             __fadd_rn(__fadd_rn(v[4], v[5]), __fadd_rn(v[6], v[7])));
        float h1 = __fadd_rn(__fadd_rn(__fadd_rn(v[8], v[9]), __fadd_rn(v[10], v[11])),
                             __fadd_rn(__fadd_rn(v[12], v[13]), __fadd_rn(v[14], v[15])));
        float nr = fmaxf(sqrtf(__fadd_rn(h0, h1)), 1e-12f);
        if (lane == 0) nrml[n] = nr;
    } else {
        int n = (bid - NTOK / 4) * 4 + wid;
        const float* row = cb + (size_t)n * DIM;
        int d0 = lane * 4;
        float4 xv = *(const float4*)(row + d0);
        // fp32 numpy-exact norm chain + fp64 sq chain
        const float* p = row + h * 128;
        float r = __fmul_rn(p[j], p[j]);
        double ds = 0.0;
#pragma unroll
        for (int i = 8; i < 128; i += 8)
            r = __fadd_rn(r, __fmul_rn(p[i + j], p[i + j]));
#pragma unroll
        for (int i = 0; i < 128; i += 8) { double vv = (double)p[i + j]; ds += vv * vv; }
        float v[16];
#pragma unroll
        for (int l = 0; l < 16; ++l) v[l] = __shfl(r, l, 64);
        float h0 = __fadd_rn(__fadd_rn(__fadd_rn(v[0], v[1]), __fadd_rn(v[2], v[3])),
                             __fadd_rn(__fadd_rn(v[4], v[5]), __fadd_rn(v[6], v[7])));
        float h1 = __fadd_rn(__fadd_rn(__fadd_rn(v[8], v[9]), __fadd_rn(v[10], v[11])),
                             __fadd_rn(__fadd_rn(v[12], v[13]), __fadd_rn(v[14], v[15])));
        float nr = fmaxf(sqrtf(__fadd_rn(h0, h1)), 1e-12f);
        // fp64 sum: butterfly reduce (feeds tolerance-checked pairwise outputs only)
#pragma unroll
        for (int off = 1; off < 16; off <<= 1) ds += __shfl_xor(ds, off, 16);
        if (lane == 0) { nrmc[n] = nr; sq[n] = (float)ds; }
        ushort4 cn, cbv;
        cn.x = f2bf(xv.x / nr); cn.y = f2bf(xv.y / nr);
        cn.z = f2bf(xv.z / nr); cn.w = f2bf(xv.w / nr);
        cbv.x = f2bf(xv.x); cbv.y = f2bf(xv.y); cbv.z = f2bf(xv.z); cbv.w = f2bf(xv.w);
        *(ushort4*)(cnbf + (size_t)n * DIM + d0) = cn;
        *(ushort4*)(cbbf + (size_t)n * DIM + d0) = cbv;
    }
}

// ---- merged GEMM kernel: 512 threads, 8 waves x (64 rows x 128 cols) over 256x256 ----
// Counted-vmcnt pipeline (T4): two K-tiles in flight, never drain to 0 mid-loop.
// Epilogue insertion networks use v_med3_u32 (top-2: max+med3; top-4: max+3*med3).
// blocks [0, NSCOB2): score tiles -> top-4 keys per (row, 128-colblk)
// blocks [NSCOB2, +NTRI2): codebook pairwise upper-triangle tiles -> sum/min
__global__ __launch_bounds__(512, 2) void gemms(const ushort* __restrict__ latbf,
                                                const ushort* __restrict__ cnbf,
                                                const ushort* __restrict__ cbbf,
                                                const float* __restrict__ sq,
                                                unsigned* __restrict__ keysw,
                                                float* __restrict__ psumw,
                                                unsigned* __restrict__ pminw) {
    __shared__ TileSmem sm;
    int tid = threadIdx.x;
    int wave = tid >> 6, lane = tid & 63;
    int quad = lane >> 4, l15 = lane & 15;
    int wr = wave >> 1, wc = wave & 1;   // 4x2 wave grid: each wave 64 rows x 128 cols
    bool isScore = blockIdx.x < NSCOB2;
    int rowBase, colBase, tri = 0, cbk = 0;
    const ushort *gA, *gB;
    if (isScore) {
        cbk = blockIdx.x & 15;
        int rbk = blockIdx.x >> 4;
        rowBase = rbk * 256; colBase = cbk * 256;
        gA = latbf + (size_t)rowBase * DIM;
        gB = cnbf + (size_t)colBase * DIM;
    } else {
        tri = blockIdx.x - NSCOB2;
        int a = (int)((sqrtf(8.f * tri + 1.f) - 1.f) * 0.5f);
        while ((a + 1) * (a + 2) / 2 <= tri) ++a;
        while (a * (a + 1) / 2 > tri) --a;
        int b = tri - a * (a + 1) / 2;   // a >= b
        rowBase = b * 256; colBase = a * 256;
        gA = cbbf + (size_t)rowBase * DIM;
        gB = cbbf + (size_t)colBase * DIM;
    }
    floatx4 acc[4][8];
#pragma unroll
    for (int m = 0; m < 4; ++m)
#pragma unroll
        for (int n = 0; n < 8; ++n) acc[m][n] = (floatx4){0.f, 0.f, 0.f, 0.f};

    // prologue: two tiles in flight
    stage_tile8(gA, gB, sm.t[0].a, sm.t[0].b, wave, lane, 0);
    stage_tile8(gA, gB, sm.t[1].a, sm.t[1].b, wave, lane, 64);
#pragma unroll
    for (int t = 0; t < 4; ++t) {
        int cur = t & 1;
        if (t < 3)
            asm volatile("s_waitcnt vmcnt(8)" ::: "memory");
        else
            asm volatile("s_waitcnt vmcnt(0)" ::: "memory");
        __builtin_amdgcn_s_barrier();
#pragma unroll
        for (int s = 0; s < 2; ++s) {
            shortx8 af[4], bfv[8];
#pragma unroll
            for (int mt = 0; mt < 4; ++mt)
                af[mt] = frag_read(sm.t[cur].a, wr * 64 + mt * 16 + l15, s * 4 + quad);
#pragma unroll
            for (int nt = 0; nt < 8; ++nt)
                bfv[nt] = frag_read(sm.t[cur].b, wc * 128 + nt * 16 + l15, s * 4 + quad);
            __builtin_amdgcn_s_setprio(1);
#pragma unroll
            for (int mt = 0; mt < 4; ++mt)
#pragma unroll
                for (int nt = 0; nt < 8; ++nt)
                    acc[mt][nt] = __builtin_amdgcn_mfma_f32_16x16x32_bf16(
                        af[mt], bfv[nt], acc[mt][nt], 0, 0, 0);
            __builtin_amdgcn_s_setprio(0);
        }
        __builtin_amdgcn_s_barrier();
        if (t < 2)
            stage_tile8(gA, gB, sm.t[cur].a, sm.t[cur].b, wave, lane, (t + 2) * 64);
    }
    __syncthreads();   // tiles dead; reuse LDS for epilogue
    if (isScore) {
        // key = (fmax(score,0) bits, top 19) | sign-tag | colp.  Negatives collapse
        // to +0.0 keys: they can never sit within DELTA of the (positive) row max,
        // and a spurious candidate would lose the exact fp64 re-score anyway.
        unsigned colp2[8];
#pragma unroll
        for (int nt = 0; nt < 8; ++nt)
            colp2[nt] = 0x80000000u | (4095u - (unsigned)(colBase + wc * 128 + nt * 16 + l15));
#pragma unroll
        for (int mt = 0; mt < 4; ++mt)
#pragma unroll
            for (int reg = 0; reg < 4; ++reg) {
                unsigned b1 = 0u, b2 = 0u;
#pragma unroll
                for (int nt = 0; nt < 8; ++nt) {
                    // (bits & M) | colp -> v_and_or_b32; top-2 via max + med3
                    unsigned key = (__float_as_uint(fmaxf(acc[mt][nt][reg], 0.f)) & 0x7FFFF000u)
                                   | colp2[nt];
                    unsigned o1 = b1;
                    b1 = max(b1, key);
                    b2 = med3u(o1, b2, key);
                }
                int row = wr * 64 + mt * 16 + quad * 4 + reg;
                uint2 kv; kv.x = b1; kv.y = b2;
                *(uint2*)&sm.keys[row][(wc * 16 + l15) * 2] = kv;
            }
        __syncthreads();
        {
            // per (row, 128-col half): 32 keys; one thread folds each -> top-4
            // sorted-insert: a0>=a1>=a2>=a3; new v: max + med3(old_k-1, old_k, v)
            int prow = tid >> 1, hh = tid & 1;
            unsigned a0 = 0, a1 = 0, a2 = 0, a3 = 0;
#pragma unroll
            for (int j2 = 0; j2 < 8; ++j2) {
                uint4 v4 = *(const uint4*)&sm.keys[prow][hh * 32 + j2 * 4];
                unsigned vs[4] = {v4.x, v4.y, v4.z, v4.w};
#pragma unroll
                for (int q = 0; q < 4; ++q) {
                    unsigned v = vs[q];
                    unsigned o0 = a0, o1 = a1, o2 = a2;
                    a0 = max(o0, v);
                    a1 = med3u(o0, a1, v);
                    a2 = med3u(o1, a2, v);
                    a3 = med3u(o2, a3, v);
                }
            }
            size_t base = (size_t)(rowBase + prow) * NKROW + (size_t)(cbk * 2 + hh) * NKEY;
            uint4 o; o.x = a0; o.y = a1; o.z = a2; o.w = a3;
            *(uint4*)&keysw[base] = o;
        }
    } else {
        float lsum = 0.f, lmin = INFINITY;
#pragma unroll
        for (int mt = 0; mt < 4; ++mt)
#pragma unroll
            for (int reg = 0; reg < 4; ++reg) {
                int i = rowBase + wr * 64 + mt * 16 + quad * 4 + reg;
                float sqi = sq[i];
#pragma unroll
                for (int nt = 0; nt < 8; ++nt) {
                    int j2 = colBase + wc * 128 + nt * 16 + l15;
                    float d2 = sqi + sq[j2] - 2.0f * acc[mt][nt][reg];
                    float d = sqrtf(fmaxf(d2, 0.0f));
                    bool use = i < j2;
                    lsum += use ? d : 0.f;
                    lmin = fminf(lmin, use ? d : INFINITY);
                }
            }
        sm.red.rs[tid] = lsum; sm.red.rm[tid] = lmin; __syncthreads();
        for (int s = 256; s > 0; s >>= 1) {
            if (tid < s) {
                sm.red.rs[tid] += sm.red.rs[tid + s];
                sm.red.rm[tid] = fminf(sm.red.rm[tid], sm.red.rm[tid + s]);
            }
            __syncthreads();
        }
        if (tid == 0) { psumw[tri] = sm.red.rs[0]; pminw[tri] = f2ord(sm.red.rm[0]); }
    }
}

// ---- wave-per-row argmax resolve + fused quantized gather/mse ----
__global__ __launch_bounds__(256) void argmax_resolve(const float* __restrict__ lat,
                                                      const float* __restrict__ cb,
                                                      const float* __restrict__ nrml,
                                                      const float* __restrict__ nrmc,
                                                      const unsigned* __restrict__ keysw,
                                                      float* __restrict__ outidx,
                                                      float* __restrict__ outq,
                                                      unsigned* __restrict__ counts,
                                                      float* __restrict__ selw,
                                                      float* __restrict__ msew) {
    __shared__ int scand[4][MAXC];
    __shared__ double sc64[4][MAXC];
    int wid = threadIdx.x >> 6, lane = threadIdx.x & 63;
    int n = blockIdx.x * 4 + wid;
    const unsigned* kr = keysw + (size_t)n * NKROW;
    uint2 kv = *(const uint2*)(kr + lane * 2);
    unsigned m = max(kv.x, kv.y);
#pragma unroll
    for (int off = 1; off < 64; off <<= 1) {
        unsigned o = __shfl_xor(m, off, 64);
        m = max(m, o);
    }
    float v1 = ord2f(m & 0xFFFFF000u);
    float thresh = v1 - DELTA;
    bool p0 = ord2f(kv.x & 0xFFFFF000u) >= thresh;
    bool p1 = ord2f(kv.y & 0xFFFFF000u) >= thresh;
    ull b0 = __ballot(p0), b1 = __ballot(p1);
    int below0 = __builtin_amdgcn_mbcnt_hi((unsigned)(b0 >> 32),
                 __builtin_amdgcn_mbcnt_lo((unsigned)b0, 0));
    int below1 = __builtin_amdgcn_mbcnt_hi((unsigned)(b1 >> 32),
                 __builtin_amdgcn_mbcnt_lo((unsigned)b1, 0));
    int base1 = __popcll(b0);
    int nc = base1 + __popcll(b1);
    if (p0 && below0 < MAXC)
        scand[wid][below0] = 4095 - (int)(kv.x & 0xFFFu);
    if (p1 && base1 + below1 < MAXC)
        scand[wid][base1 + below1] = 4095 - (int)(kv.y & 0xFFFu);
    nc = nc < MAXC ? nc : MAXC;
    __threadfence_block();
    float nx = nrml[n];
    int d0 = lane * 4;
    float4 xv = *(const float4*)(lat + (size_t)n * DIM + d0);
    int idx; float selcos;
    if (nc <= 1) {
        idx = 4095 - (int)(m & 0xFFFu);
        selcos = v1 / nx;
    } else {
        float la0 = xv.x / nx, la1 = xv.y / nx, la2 = xv.z / nx, la3 = xv.w / nx;
        for (int c = 0; c < nc; ++c) {
            int k = scand[wid][c];
            float nk = nrmc[k];
            float4 cv = *(const float4*)(cb + (size_t)k * DIM + d0);
            double part = (double)(cv.x / nk) * la0 + (double)(cv.y / nk) * la1 +
                          (double)(cv.z / nk) * la2 + (double)(cv.w / nk) * la3;
#pragma unroll
            for (int off = 1; off < 64; off <<= 1) part += __shfl_xor(part, off, 64);
            if (lane == 0) sc64[wid][c] = part;
        }
        __threadfence_block();
        double best64 = -1e300;
        for (int c = 0; c < nc; ++c) best64 = fmax(best64, sc64[wid][c]);
        int nrisk = 0;
        for (int c = 0; c < nc; ++c) if (sc64[wid][c] >= best64 - GTIE) ++nrisk;
        if (nrisk == 1) {
            idx = 0x7FFFFFFF; selcos = 0.f;
            for (int c = 0; c < nc; ++c)
                if (sc64[wid][c] >= best64 - GTIE) { idx = scand[wid][c]; selcos = (float)sc64[wid][c]; }
        } else {
            // rare: bit-exact np fp32 chains, one candidate per lane (R4 semantics)
            ull keyf = 0ull, keym = 0ull;
            if (lane < nc && sc64[wid][lane] >= best64 - GTIE) {
                int k = scand[wid][lane];
                const float* cr = cb + (size_t)k * DIM;
                const float* x = lat + (size_t)n * DIM;
                float nk = nrmc[k];
                float af = 0.f, am = 0.f;
                for (int d = 0; d < DIM; ++d) {
                    float la = x[d] / nx;
                    float cv = cr[d] / nk;
                    af = fmaf(la, cv, af);
                    am = __fadd_rn(am, __fmul_rn(la, cv));
                }
                float df = __fsub_rn(2.0f, __fmul_rn(2.0f, af));
                float dm = __fsub_rn(2.0f, __fmul_rn(2.0f, am));
                keyf = ((ull)(0xFFFFFFFFu - f2ord(df)) << 32) | (ull)(0xFFFFFFFFu - (unsigned)k);
                keym = ((ull)(0xFFFFFFFFu - f2ord(dm)) << 32) | (ull)(0xFFFFFFFFu - (unsigned)k);
            }
#pragma unroll
            for (int off = 1; off < 64; off <<= 1) {
                ull of = __shfl_xor(keyf, off, 64);
                ull om = __shfl_xor(keym, off, 64);
                keyf = of > keyf ? of : keyf;
                keym = om > keym ? om : keym;
            }
            int colf = (int)(0xFFFFFFFFu - (unsigned)(keyf & 0xFFFFFFFFull));
            int colm = (int)(0xFFFFFFFFu - (unsigned)(keym & 0xFFFFFFFFull));
            idx = colf < colm ? colf : colm;
            selcos = 0.f;
            for (int c = 0; c < nc; ++c)
                if (scand[wid][c] == idx) selcos = (float)sc64[wid][c];
        }
    }
    // fused gather: idx is wave-uniform on every path
    float4 qv = *(const float4*)(cb + (size_t)idx * DIM + d0);
    *(float4*)(outq + (size_t)n * DIM + d0) = qv;
    float dx = xv.x - qv.x, dy = xv.y - qv.y, dz = xv.z - qv.z, dw = xv.w - qv.w;
    float msep = fmaf(dx, dx, fmaf(dy, dy, fmaf(dz, dz, dw * dw)));
#pragma unroll
    for (int off = 1; off < 64; off <<= 1) msep += __shfl_xor(msep, off, 64);
    if (lane == 0) {
        outidx[n] = (float)idx;
        atomicAdd(&counts[idx], 1u);
        selw[n] = selcos;
        msew[n] = msep;
    }
}

// ---- scalars: reduce all partial arrays ----
__global__ void finalize(const unsigned* __restrict__ counts,
                         const float* __restrict__ selw,
                         const float* __restrict__ msew,
                         const float* __restrict__ psumw,
                         const unsigned* __restrict__ pminw,
                         float* __restrict__ outs) {
    int t = threadIdx.x;
    __shared__ float red[256];
    float h = 0.f;
    for (int k = t; k < KCB; k += 256) {
        float p = (float)counts[k] * (1.0f / (float)NTOK);
        h += p * logf(p + 1e-10f);
    }
    red[t] = h; __syncthreads();
    for (int s = 128; s > 0; s >>= 1) { if (t < s) red[t] += red[t + s]; __syncthreads(); }
    float entNeg = red[0];
    __syncthreads();
    float ssel = 0.f;
    for (int k = t; k < NTOK; k += 256) ssel += selw[k];
    red[t] = ssel; __syncthreads();
    for (int s = 128; s > 0; s >>= 1) { if (t < s) red[t] += red[t + s]; __syncthreads(); }
    float selSum = red[0];
    __syncthreads();
    float sm = 0.f;
    for (int k = t; k < NTOK; k += 256) sm += msew[k];
    red[t] = sm; __syncthreads();
    for (int s = 128; s > 0; s >>= 1) { if (t < s) red[t] += red[t + s]; __syncthreads(); }
    float mseSum = red[0];
    __syncthreads();
    float ps = 0.f;
    for (int k = t; k < NPAIRB; k += 256) ps += psumw[k];
    red[t] = ps; __syncthreads();
    for (int s = 128; s > 0; s >>= 1) { if (t < s) red[t] += red[t + s]; __syncthreads(); }
    float pairSum = red[0];
    __syncthreads();
    unsigned pm = 0xFFFFFFFFu;
    for (int k = t; k < NPAIRB; k += 256) pm = min(pm, pminw[k]);
    ((unsigned*)red)[t] = pm; __syncthreads();
    for (int s = 128; s > 0; s >>= 1) {
        if (t < s) ((unsigned*)red)[t] = min(((unsigned*)red)[t], ((unsigned*)red)[t + s]);
        __syncthreads();
    }
    unsigned pairMin = ((unsigned*)red)[0];
    if (t == 0) {
        float mse = mseSum / (float)(NTOK * DIM);
        outs[0] = 0.25f * mse;
        outs[1] = mse;
        outs[2] = expf(-entNeg);
        outs[3] = selSum / (float)NTOK;
        outs[4] = pairSum * 2.0f / ((float)KCB * (float)(KCB - 1));
        outs[5] = ord2f(pairMin);
    }
}

extern "C" void kernel_launch(void* const* d_in, const int* in_sizes, int n_in,
                              void* d_out, int out_size, void* d_ws, size_t ws_size,
                              hipStream_t stream) {
    const float* latent = (const float*)d_in[0];    // [8192,256]
    const float* codebook = (const float*)d_in[1];  // [4096,256]
    float* out = (float*)d_out;
    float* outq = out;
    float* outidx = out + (size_t)NTOK * DIM;
    float* outs = outidx + NTOK;

    unsigned* keysw = (unsigned*)d_ws;                        // 128*8192 u32 = 4 MB
    ushort* latbf = (ushort*)(keysw + (size_t)NKROW * NTOK);  // 4 MB
    ushort* cnbf = latbf + (size_t)NTOK * DIM;                // 2 MB
    ushort* cbbf = cnbf + (size_t)KCB * DIM;                  // 2 MB
    float* nrml = (float*)(cbbf + (size_t)KCB * DIM);         // 8192
    float* nrmc = nrml + NTOK;                                // 4096
    float* sq = nrmc + KCB;                                   // 4096
    unsigned* counts = (unsigned*)(sq + KCB);                 // 4096
    float* selw = (float*)(counts + KCB);                     // 8192
    float* msew = selw + NTOK;                                // 8192
    float* psumw = msew + NTOK;                               // 528 (only NPAIRB=136 used)
    unsigned* pminw = (unsigned*)(psumw + 528);               // 528 (only NPAIRB=136 used)

    hipLaunchKernelGGL(prep, dim3(NTOK / 4 + KCB / 4), dim3(256), 0, stream,
                       latent, codebook, nrml, nrmc, latbf, cnbf, cbbf, sq, counts);
    hipLaunchKernelGGL(gemms, dim3(NSCOB2 + NTRI2), dim3(512), 0, stream,
                       latbf, cnbf, cbbf, sq, keysw, psumw, pminw);
    hipLaunchKernelGGL(argmax_resolve, dim3(NTOK / 4), dim3(256), 0, stream,
                       latent, codebook, nrml, nrmc, keysw, outidx, outq, counts, selw, msew);
    hipLaunchKernelGGL(finalize, dim3(1), dim3(256), 0, stream, counts, selw, msew, psumw, pminw, outs);
}